// Round 15
// baseline (36.298 us; speedup 1.0000x reference)
//
#include <hip/hip_runtime.h>

typedef _Float16 h2 __attribute__((ext_vector_type(2)));
typedef _Float16 h8 __attribute__((ext_vector_type(8)));
typedef float    f4 __attribute__((ext_vector_type(4)));

// Row permutation: MFMA C/D layout == next layer's B-fragment layout after pack
#define PI(t,r) (8*((r)>>2) + ((r)&3) + 4*((t)&1) + 32*((t)>>1))

// Per-lane fragment blob in LDS (staging only; read ONCE per wave, then
// pinned in arch VGPRs). 27 frags x 16B, stride 29 f4, conflict-free (r4/r8:
// SQ_LDS_BANK_CONFLICT == 0).
#define FSTRIDE 29
// frag indices: 0-7 A2[t][c] (2t+c) | 8-15 A3[t][c] | 16-17 Ah[c]
//               18-21 bC2[t] | 22-25 bC3[t] | 26 bCh

union Frag { h8 v; h2 q[4]; f4 f; };

__device__ __forceinline__ h2 relu2(h2 a) {
    const h2 z = {};
    return __builtin_elementwise_max(a, z);   // v_pk_max_f16
}

__device__ __forceinline__ h2 pkrtz(float a, float b) {
    return __builtin_bit_cast(h2, __builtin_amdgcn_cvt_pkrtz(a, b));
}

// Split-K pack: relu + f16-pack (aA + aB), the two independent K-chunk
// accumulators, into B-fragments. The adds sit on the VALU (4 cyc dep) and
// replace a full dependent-MFMA level (2 MFMA levels/layer -> 1).
__device__ __forceinline__ void packB2(const f4 (&aA)[4], const f4 (&aB)[4],
                                       Frag (&B)[2]) {
    #pragma unroll
    for (int c = 0; c < 2; ++c) {
        #pragma unroll
        for (int hh = 0; hh < 2; ++hh) {
            const int t = 2*c + hh;
            B[c].q[2*hh + 0] = relu2(pkrtz(aA[t][0] + aB[t][0], aA[t][1] + aB[t][1]));
            B[c].q[2*hh + 1] = relu2(pkrtz(aA[t][2] + aB[t][2], aA[t][3] + aB[t][3]));
        }
    }
}

__global__ __launch_bounds__(256, 2)
void pihp_mfma(const float* __restrict__ pc,
               const float* __restrict__ W1, const float* __restrict__ b1,
               const float* __restrict__ W2, const float* __restrict__ b2,
               const float* __restrict__ W3, const float* __restrict__ b3,
               const float* __restrict__ Wmu, const float* __restrict__ bmu,
               const float* __restrict__ Wlam, const float* __restrict__ blam,
               float* __restrict__ out, int N)
{
    __shared__ f4 wblob[64 * FSTRIDE];

    const int tid  = threadIdx.x;
    const int lane = tid & 63;
    const int g    = lane >> 4;
    const int m    = lane & 15;
    const int sec  = tid >> 6;           // wave id within block: gather section

    // ---------------- cooperative fragment gather into LDS ----------------
    f4* myw = &wblob[lane * FSTRIDE];
    if (sec == 0) {
        #pragma unroll
        for (int t = 0; t < 2; ++t)
            #pragma unroll
            for (int c = 0; c < 2; ++c) {
                Frag fr;
                #pragma unroll
                for (int ii = 0; ii < 8; ++ii)
                    fr.v[ii] = (_Float16)W2[(32*c + 8*g + ii)*64 + PI(t, m)];
                myw[2*t + c] = fr.f;
            }
        #pragma unroll
        for (int c = 0; c < 2; ++c) {
            Frag fr;
            #pragma unroll
            for (int ii = 0; ii < 8; ++ii) {
                const int k = 32*c + 8*g + ii;
                float v = 0.0f;
                if (m < 4)      v = Wmu[k*4 + m];
                else if (m < 7) v = Wlam[k*3 + (m - 4)];
                fr.v[ii] = (_Float16)v;
            }
            myw[16 + c] = fr.f;
        }
    } else if (sec == 1) {
        #pragma unroll
        for (int t = 2; t < 4; ++t)
            #pragma unroll
            for (int c = 0; c < 2; ++c) {
                Frag fr;
                #pragma unroll
                for (int ii = 0; ii < 8; ++ii)
                    fr.v[ii] = (_Float16)W2[(32*c + 8*g + ii)*64 + PI(t, m)];
                myw[2*t + c] = fr.f;
            }
        #pragma unroll
        for (int t = 0; t < 4; ++t) {
            f4 bb;
            #pragma unroll
            for (int i = 0; i < 4; ++i) bb[i] = b2[PI(t, 4*g + i)];
            myw[18 + t] = bb;
        }
    } else if (sec == 2) {
        #pragma unroll
        for (int t = 0; t < 2; ++t)
            #pragma unroll
            for (int c = 0; c < 2; ++c) {
                Frag fr;
                #pragma unroll
                for (int ii = 0; ii < 8; ++ii)
                    fr.v[ii] = (_Float16)W3[(32*c + 8*g + ii)*64 + PI(t, m)];
                myw[8 + 2*t + c] = fr.f;
            }
        #pragma unroll
        for (int t = 0; t < 4; ++t) {
            f4 bb;
            #pragma unroll
            for (int i = 0; i < 4; ++i) bb[i] = b3[PI(t, 4*g + i)];
            myw[22 + t] = bb;
        }
    } else {
        #pragma unroll
        for (int t = 2; t < 4; ++t)
            #pragma unroll
            for (int c = 0; c < 2; ++c) {
                Frag fr;
                #pragma unroll
                for (int ii = 0; ii < 8; ++ii)
                    fr.v[ii] = (_Float16)W3[(32*c + 8*g + ii)*64 + PI(t, m)];
                myw[8 + 2*t + c] = fr.f;
            }
        f4 bb;
        #pragma unroll
        for (int i = 0; i < 4; ++i) {
            const int rr = 4*g + i;
            bb[i] = (rr < 4) ? bmu[rr] : (rr < 7 ? blam[rr - 4] : 0.0f);
        }
        myw[26] = bb;
    }

    // Layer-1 weights resident (12 VGPR)
    h2 w1x[2][4], w1y[2][4], w1b[2][4];
    #pragma unroll
    for (int c = 0; c < 2; ++c)
        #pragma unroll
        for (int p = 0; p < 4; ++p) {
            const int k = 32*c + 8*g + 2*p;
            w1x[c][p][0] = (_Float16)W1[k];      w1x[c][p][1] = (_Float16)W1[k+1];
            w1y[c][p][0] = (_Float16)W1[64+k];   w1y[c][p][1] = (_Float16)W1[64+k+1];
            w1b[c][p][0] = (_Float16)b1[k];      w1b[c][p][1] = (_Float16)b1[k+1];
        }

    __syncthreads();

    // -------- read all fragments into arch VGPRs once, pin with asm --------
    h8 A2f[4][2], A3f[4][2], Ahf[2];
    f4 bC2[4], bC3[4], bCh;
    #pragma unroll
    for (int t = 0; t < 4; ++t)
        #pragma unroll
        for (int c = 0; c < 2; ++c) {
            A2f[t][c] = __builtin_bit_cast(h8, myw[2*t + c]);
            A3f[t][c] = __builtin_bit_cast(h8, myw[8 + 2*t + c]);
        }
    #pragma unroll
    for (int c = 0; c < 2; ++c) Ahf[c] = __builtin_bit_cast(h8, myw[16 + c]);
    #pragma unroll
    for (int t = 0; t < 4; ++t) { bC2[t] = myw[18 + t]; bC3[t] = myw[22 + t]; }
    bCh = myw[26];

    #pragma unroll
    for (int t = 0; t < 4; ++t)
        #pragma unroll
        for (int c = 0; c < 2; ++c) {
            asm volatile("" : "+v"(A2f[t][c]));
            asm volatile("" : "+v"(A3f[t][c]));
        }
    #pragma unroll
    for (int c = 0; c < 2; ++c) asm volatile("" : "+v"(Ahf[c]));
    #pragma unroll
    for (int t = 0; t < 4; ++t) {
        asm volatile("" : "+v"(bC2[t]));
        asm volatile("" : "+v"(bC3[t]));
    }
    asm volatile("" : "+v"(bCh));

    // ---------------- work split ----------------
    const int wid = blockIdx.x * (blockDim.x >> 6) + sec;
    const int nw  = gridDim.x * (blockDim.x >> 6);
    const int nslab = (N + 15) >> 4;
    int per = (nslab + nw - 1) / nw;
    per = (per + 1) & ~1;                           // even
    const int s0 = wid * per;
    if (s0 >= nslab) return;
    const int s1 = (s0 + per < nslab) ? (s0 + per) : nslab;

    float* const pl0 = out;
    float* const pl1 = out + (size_t)N;
    float* const pl2 = out + (size_t)2*N;
    float* const pl3 = out + (size_t)3*N;
    float* const pl4 = out + (size_t)4*N;
    float* const pl5 = out + (size_t)5*N;
    float* const pl6 = out + (size_t)6*N;

    const float2* __restrict__ pcv = reinterpret_cast<const float2*>(pc);
    const int Nm1 = N - 1;
    auto clampload = [&](int ss) -> float2 {
        int pt = ss*16 + m;
        pt = pt < Nm1 ? pt : Nm1;                   // prefetch-safe
        return pcv[pt];
    };

    float2 Pc0 = clampload(s0);
    float2 Pc1 = clampload(s0 + 1);
    const bool isMu = (g == 0);
    const f4 z4 = {};

    #pragma unroll 1
    for (int ss = s0; ss < s1; ss += 2) {
        float2 Pn0 = clampload(ss + 2);
        float2 Pn1 = clampload(ss + 3);

        // Layer 1 (2->64) packed f16 -> B fragments
        Frag B0[2], B1[2];
        {
            const h2 x0 = pkrtz(Pc0.x, Pc0.x), y0 = pkrtz(Pc0.y, Pc0.y);
            const h2 x1 = pkrtz(Pc1.x, Pc1.x), y1 = pkrtz(Pc1.y, Pc1.y);
            #pragma unroll
            for (int c = 0; c < 2; ++c)
                #pragma unroll
                for (int p = 0; p < 4; ++p) {
                    B0[c].q[p] = relu2(x0 * w1x[c][p] + y0 * w1y[c][p] + w1b[c][p]);
                    B1[c].q[p] = relu2(x1 * w1x[c][p] + y1 * w1y[c][p] + w1b[c][p]);
                }
        }

        // Layer 2 split-K: all 16 MFMAs independent (no acc chaining);
        // K-chunk sum happens on the VALU inside packB2.
        f4 a0A[4], a0B[4], a1A[4], a1B[4];
        #pragma unroll
        for (int t = 0; t < 4; ++t) {
            a0A[t] = __builtin_amdgcn_mfma_f32_16x16x32_f16(A2f[t][0], B0[0].v, bC2[t], 0, 0, 0);
            a1A[t] = __builtin_amdgcn_mfma_f32_16x16x32_f16(A2f[t][0], B1[0].v, bC2[t], 0, 0, 0);
            a0B[t] = __builtin_amdgcn_mfma_f32_16x16x32_f16(A2f[t][1], B0[1].v, z4, 0, 0, 0);
            a1B[t] = __builtin_amdgcn_mfma_f32_16x16x32_f16(A2f[t][1], B1[1].v, z4, 0, 0, 0);
        }
        packB2(a0A, a0B, B0);
        packB2(a1A, a1B, B1);

        // Layer 3 split-K
        #pragma unroll
        for (int t = 0; t < 4; ++t) {
            a0A[t] = __builtin_amdgcn_mfma_f32_16x16x32_f16(A3f[t][0], B0[0].v, bC3[t], 0, 0, 0);
            a1A[t] = __builtin_amdgcn_mfma_f32_16x16x32_f16(A3f[t][0], B1[0].v, bC3[t], 0, 0, 0);
            a0B[t] = __builtin_amdgcn_mfma_f32_16x16x32_f16(A3f[t][1], B0[1].v, z4, 0, 0, 0);
            a1B[t] = __builtin_amdgcn_mfma_f32_16x16x32_f16(A3f[t][1], B1[1].v, z4, 0, 0, 0);
        }
        packB2(a0A, a0B, B0);
        packB2(a1A, a1B, B1);

        // Heads split-K (64->7 padded): g=0 -> mu0..3, g=1 -> lam0..2
        f4 h0a, h0b, h1a, h1b;
        h0a = __builtin_amdgcn_mfma_f32_16x16x32_f16(Ahf[0], B0[0].v, bCh, 0, 0, 0);
        h1a = __builtin_amdgcn_mfma_f32_16x16x32_f16(Ahf[0], B1[0].v, bCh, 0, 0, 0);
        h0b = __builtin_amdgcn_mfma_f32_16x16x32_f16(Ahf[1], B0[1].v, z4, 0, 0, 0);
        h1b = __builtin_amdgcn_mfma_f32_16x16x32_f16(Ahf[1], B1[1].v, z4, 0, 0, 0);
        const f4 h0 = h0a + h0b;
        const f4 h1 = h1a + h1b;

        // Branchless projection epilogue + stores (r9 layout).
        // mu: scale = min(rsqrt(ss),1) == (norm>1 ? 1/(norm+1e-8) : 1) within 1e-8
        // lam: inv = rsqrt(ss+1e-16)   == 1/(sqrt(ss)+1e-8) within ~1e-10 rel
        #pragma unroll
        for (int u = 0; u < 2; ++u) {
            const f4 hv = (u == 0) ? h0 : h1;
            const int pt = (ss + u)*16 + m;
            const float r0 = isMu ? fmaxf(hv[0], 0.0f) : hv[0];
            const float r1 = isMu ? fmaxf(hv[1], 0.0f) : hv[1];
            const float r2 = isMu ? fmaxf(hv[2], 0.0f) : hv[2];
            const float r3 = isMu ? fmaxf(hv[3], 0.0f) : hv[3];
            const float t0 = isMu ? (r0 - r1) : r0;
            const float t1 = isMu ? (r2 - r3) : r1;
            const float t2 = isMu ? 0.0f      : r2;
            const float ssum = t0*t0 + t1*t1 + t2*t2;
            const float r  = rsqrtf(ssum + 1e-16f);
            const float sc = isMu ? fminf(r, 1.0f) : r;
            if (g == 0) {
                pl0[pt] = r0 * sc;
                pl1[pt] = r1 * sc;
                pl2[pt] = r2 * sc;
                pl3[pt] = r3 * sc;
            } else if (g == 1) {
                pl4[pt] = r0 * sc;
                pl5[pt] = r1 * sc;
                pl6[pt] = r2 * sc;
            }
        }

        Pc0 = Pn0;
        Pc1 = Pn1;
    }
}

extern "C" void kernel_launch(void* const* d_in, const int* in_sizes, int n_in,
                              void* d_out, int out_size, void* d_ws, size_t ws_size,
                              hipStream_t stream) {
    const float* pc   = (const float*)d_in[0];
    const float* W1   = (const float*)d_in[1];
    const float* b1   = (const float*)d_in[2];
    const float* W2   = (const float*)d_in[3];
    const float* b2   = (const float*)d_in[4];
    const float* W3   = (const float*)d_in[5];
    const float* b3   = (const float*)d_in[6];
    const float* Wmu  = (const float*)d_in[7];
    const float* bmu  = (const float*)d_in[8];
    const float* Wlam = (const float*)d_in[9];
    const float* blam = (const float*)d_in[10];
    float* out = (float*)d_out;

    const int N = in_sizes[0] / 2;   // point_cloud is (N, 2)
    // 512 blocks x 4 waves = 2048 waves: one full resident pass at 2 waves/SIMD
    pihp_mfma<<<512, 256, 0, stream>>>(pc, W1, b1, W2, b2, W3, b3,
                                       Wmu, bmu, Wlam, blam, out, N);
}

// Round 16
// 33.136 us; speedup vs baseline: 1.0954x; 1.0954x over previous
//
#include <hip/hip_runtime.h>

typedef _Float16 h2 __attribute__((ext_vector_type(2)));
typedef _Float16 h8 __attribute__((ext_vector_type(8)));
typedef float    f4 __attribute__((ext_vector_type(4)));

// Row permutation: MFMA C/D layout == next layer's B-fragment layout after pack
#define PI(t,r) (8*((r)>>2) + ((r)&3) + 4*((t)&1) + 32*((t)>>1))

// Per-lane fragment blob in LDS (staging only; read ONCE per wave, then
// pinned in arch VGPRs). 27 frags x 16B, stride 29 f4, conflict-free (r4/r8:
// SQ_LDS_BANK_CONFLICT == 0).
#define FSTRIDE 29
// frag indices: 0-7 A2[t][c] (2t+c) | 8-15 A3[t][c] | 16-17 Ah[c]
//               18-21 bC2[t] | 22-25 bC3[t] | 26 bCh

union Frag { h8 v; h2 q[4]; f4 f; };

__device__ __forceinline__ h2 relu2(h2 a) {
    const h2 z = {};
    return __builtin_elementwise_max(a, z);   // v_pk_max_f16
}

__device__ __forceinline__ h2 pkrtz(float a, float b) {
    return __builtin_bit_cast(h2, __builtin_amdgcn_cvt_pkrtz(a, b));
}

// relu + f16-pack one slab's layer output (a[4] f32x4) into its B-fragments
__device__ __forceinline__ void packB(const f4 (&a)[4], Frag (&B)[2]) {
    #pragma unroll
    for (int c = 0; c < 2; ++c) {
        #pragma unroll
        for (int hh = 0; hh < 2; ++hh) {
            const int t = 2*c + hh;
            B[c].q[2*hh + 0] = relu2(pkrtz(a[t][0], a[t][1]));
            B[c].q[2*hh + 1] = relu2(pkrtz(a[t][2], a[t][3]));
        }
    }
}

__global__ __launch_bounds__(256, 2)
void pihp_mfma(const float* __restrict__ pc,
               const float* __restrict__ W1, const float* __restrict__ b1,
               const float* __restrict__ W2, const float* __restrict__ b2,
               const float* __restrict__ W3, const float* __restrict__ b3,
               const float* __restrict__ Wmu, const float* __restrict__ bmu,
               const float* __restrict__ Wlam, const float* __restrict__ blam,
               float* __restrict__ out, int N)
{
    __shared__ f4 wblob[64 * FSTRIDE];

    const int tid  = threadIdx.x;
    const int lane = tid & 63;
    const int g    = lane >> 4;
    const int m    = lane & 15;
    const int sec  = tid >> 6;           // wave id within block: gather section

    // ---------------- cooperative fragment gather into LDS ----------------
    f4* myw = &wblob[lane * FSTRIDE];
    if (sec == 0) {
        #pragma unroll
        for (int t = 0; t < 2; ++t)
            #pragma unroll
            for (int c = 0; c < 2; ++c) {
                Frag fr;
                #pragma unroll
                for (int ii = 0; ii < 8; ++ii)
                    fr.v[ii] = (_Float16)W2[(32*c + 8*g + ii)*64 + PI(t, m)];
                myw[2*t + c] = fr.f;
            }
        #pragma unroll
        for (int c = 0; c < 2; ++c) {
            Frag fr;
            #pragma unroll
            for (int ii = 0; ii < 8; ++ii) {
                const int k = 32*c + 8*g + ii;
                float v = 0.0f;
                if (m < 4)      v = Wmu[k*4 + m];
                else if (m < 7) v = Wlam[k*3 + (m - 4)];
                fr.v[ii] = (_Float16)v;
            }
            myw[16 + c] = fr.f;
        }
    } else if (sec == 1) {
        #pragma unroll
        for (int t = 2; t < 4; ++t)
            #pragma unroll
            for (int c = 0; c < 2; ++c) {
                Frag fr;
                #pragma unroll
                for (int ii = 0; ii < 8; ++ii)
                    fr.v[ii] = (_Float16)W2[(32*c + 8*g + ii)*64 + PI(t, m)];
                myw[2*t + c] = fr.f;
            }
        #pragma unroll
        for (int t = 0; t < 4; ++t) {
            f4 bb;
            #pragma unroll
            for (int i = 0; i < 4; ++i) bb[i] = b2[PI(t, 4*g + i)];
            myw[18 + t] = bb;
        }
    } else if (sec == 2) {
        #pragma unroll
        for (int t = 0; t < 2; ++t)
            #pragma unroll
            for (int c = 0; c < 2; ++c) {
                Frag fr;
                #pragma unroll
                for (int ii = 0; ii < 8; ++ii)
                    fr.v[ii] = (_Float16)W3[(32*c + 8*g + ii)*64 + PI(t, m)];
                myw[8 + 2*t + c] = fr.f;
            }
        #pragma unroll
        for (int t = 0; t < 4; ++t) {
            f4 bb;
            #pragma unroll
            for (int i = 0; i < 4; ++i) bb[i] = b3[PI(t, 4*g + i)];
            myw[22 + t] = bb;
        }
    } else {
        #pragma unroll
        for (int t = 2; t < 4; ++t)
            #pragma unroll
            for (int c = 0; c < 2; ++c) {
                Frag fr;
                #pragma unroll
                for (int ii = 0; ii < 8; ++ii)
                    fr.v[ii] = (_Float16)W3[(32*c + 8*g + ii)*64 + PI(t, m)];
                myw[8 + 2*t + c] = fr.f;
            }
        f4 bb;
        #pragma unroll
        for (int i = 0; i < 4; ++i) {
            const int rr = 4*g + i;
            bb[i] = (rr < 4) ? bmu[rr] : (rr < 7 ? blam[rr - 4] : 0.0f);
        }
        myw[26] = bb;
    }

    // Layer-1 weights resident (12 VGPR)
    h2 w1x[2][4], w1y[2][4], w1b[2][4];
    #pragma unroll
    for (int c = 0; c < 2; ++c)
        #pragma unroll
        for (int p = 0; p < 4; ++p) {
            const int k = 32*c + 8*g + 2*p;
            w1x[c][p][0] = (_Float16)W1[k];      w1x[c][p][1] = (_Float16)W1[k+1];
            w1y[c][p][0] = (_Float16)W1[64+k];   w1y[c][p][1] = (_Float16)W1[64+k+1];
            w1b[c][p][0] = (_Float16)b1[k];      w1b[c][p][1] = (_Float16)b1[k+1];
        }

    __syncthreads();

    // -------- read all fragments into arch VGPRs once, pin with asm --------
    h8 A2f[4][2], A3f[4][2], Ahf[2];
    f4 bC2[4], bC3[4], bCh;
    #pragma unroll
    for (int t = 0; t < 4; ++t)
        #pragma unroll
        for (int c = 0; c < 2; ++c) {
            A2f[t][c] = __builtin_bit_cast(h8, myw[2*t + c]);
            A3f[t][c] = __builtin_bit_cast(h8, myw[8 + 2*t + c]);
        }
    #pragma unroll
    for (int c = 0; c < 2; ++c) Ahf[c] = __builtin_bit_cast(h8, myw[16 + c]);
    #pragma unroll
    for (int t = 0; t < 4; ++t) { bC2[t] = myw[18 + t]; bC3[t] = myw[22 + t]; }
    bCh = myw[26];

    #pragma unroll
    for (int t = 0; t < 4; ++t)
        #pragma unroll
        for (int c = 0; c < 2; ++c) {
            asm volatile("" : "+v"(A2f[t][c]));
            asm volatile("" : "+v"(A3f[t][c]));
        }
    #pragma unroll
    for (int c = 0; c < 2; ++c) asm volatile("" : "+v"(Ahf[c]));
    #pragma unroll
    for (int t = 0; t < 4; ++t) {
        asm volatile("" : "+v"(bC2[t]));
        asm volatile("" : "+v"(bC3[t]));
    }
    asm volatile("" : "+v"(bCh));

    // ---------------- work split ----------------
    const int wid = blockIdx.x * (blockDim.x >> 6) + sec;
    const int nw  = gridDim.x * (blockDim.x >> 6);
    const int nslab = (N + 15) >> 4;
    int per = (nslab + nw - 1) / nw;
    per = (per + 1) & ~1;                           // even
    const int s0 = wid * per;
    if (s0 >= nslab) return;
    const int s1 = (s0 + per < nslab) ? (s0 + per) : nslab;

    float* const pl0 = out;
    float* const pl1 = out + (size_t)N;
    float* const pl2 = out + (size_t)2*N;
    float* const pl3 = out + (size_t)3*N;
    float* const pl4 = out + (size_t)4*N;
    float* const pl5 = out + (size_t)5*N;
    float* const pl6 = out + (size_t)6*N;

    const float2* __restrict__ pcv = reinterpret_cast<const float2*>(pc);
    const int Nm1 = N - 1;
    auto clampload = [&](int ss) -> float2 {
        int pt = ss*16 + m;
        pt = pt < Nm1 ? pt : Nm1;                   // prefetch-safe
        return pcv[pt];
    };

    float2 Pc0 = clampload(s0);
    float2 Pc1 = clampload(s0 + 1);
    const bool isMu = (g == 0);

    #pragma unroll 1
    for (int ss = s0; ss < s1; ss += 2) {
        float2 Pn0 = clampload(ss + 2);
        float2 Pn1 = clampload(ss + 3);

        // Layer 1 (2->64) packed f16 -> B fragments
        Frag B0[2], B1[2];
        {
            const h2 x0 = pkrtz(Pc0.x, Pc0.x), y0 = pkrtz(Pc0.y, Pc0.y);
            const h2 x1 = pkrtz(Pc1.x, Pc1.x), y1 = pkrtz(Pc1.y, Pc1.y);
            #pragma unroll
            for (int c = 0; c < 2; ++c)
                #pragma unroll
                for (int p = 0; p < 4; ++p) {
                    B0[c].q[p] = relu2(x0 * w1x[c][p] + y0 * w1y[c][p] + w1b[c][p]);
                    B1[c].q[p] = relu2(x1 * w1x[c][p] + y1 * w1y[c][p] + w1b[c][p]);
                }
        }

        f4 a0[4], a1[4];

        // Layer 2 (all operands in registers)
        #pragma unroll
        for (int t = 0; t < 4; ++t) {
            a0[t] = __builtin_amdgcn_mfma_f32_16x16x32_f16(A2f[t][0], B0[0].v, bC2[t], 0, 0, 0);
            a1[t] = __builtin_amdgcn_mfma_f32_16x16x32_f16(A2f[t][0], B1[0].v, bC2[t], 0, 0, 0);
        }
        #pragma unroll
        for (int t = 0; t < 4; ++t) {
            a0[t] = __builtin_amdgcn_mfma_f32_16x16x32_f16(A2f[t][1], B0[1].v, a0[t], 0, 0, 0);
            a1[t] = __builtin_amdgcn_mfma_f32_16x16x32_f16(A2f[t][1], B1[1].v, a1[t], 0, 0, 0);
        }
        packB(a0, B0);
        packB(a1, B1);

        // Layer 3
        #pragma unroll
        for (int t = 0; t < 4; ++t) {
            a0[t] = __builtin_amdgcn_mfma_f32_16x16x32_f16(A3f[t][0], B0[0].v, bC3[t], 0, 0, 0);
            a1[t] = __builtin_amdgcn_mfma_f32_16x16x32_f16(A3f[t][0], B1[0].v, bC3[t], 0, 0, 0);
        }
        #pragma unroll
        for (int t = 0; t < 4; ++t) {
            a0[t] = __builtin_amdgcn_mfma_f32_16x16x32_f16(A3f[t][1], B0[1].v, a0[t], 0, 0, 0);
            a1[t] = __builtin_amdgcn_mfma_f32_16x16x32_f16(A3f[t][1], B1[1].v, a1[t], 0, 0, 0);
        }
        packB(a0, B0);
        packB(a1, B1);

        // Heads (64->7 padded): g=0 -> mu0..3, g=1 -> lam0..2
        f4 h0, h1;
        h0 = __builtin_amdgcn_mfma_f32_16x16x32_f16(Ahf[0], B0[0].v, bCh, 0, 0, 0);
        h1 = __builtin_amdgcn_mfma_f32_16x16x32_f16(Ahf[0], B1[0].v, bCh, 0, 0, 0);
        h0 = __builtin_amdgcn_mfma_f32_16x16x32_f16(Ahf[1], B0[1].v, h0, 0, 0, 0);
        h1 = __builtin_amdgcn_mfma_f32_16x16x32_f16(Ahf[1], B1[1].v, h1, 0, 0, 0);

        // Branchless projection epilogue + stores. N % 16 == 0 and per even
        // => all pt in range (no store guard needed).
        // mu: scale = min(rsqrt(ss),1) == (norm>1 ? 1/(norm+1e-8) : 1) within 1e-8
        // lam: inv = rsqrt(ss+1e-16)   == 1/(sqrt(ss)+1e-8) within ~1e-10 rel
        #pragma unroll
        for (int u = 0; u < 2; ++u) {
            const f4 hv = (u == 0) ? h0 : h1;
            const int pt = (ss + u)*16 + m;
            const float r0 = isMu ? fmaxf(hv[0], 0.0f) : hv[0];
            const float r1 = isMu ? fmaxf(hv[1], 0.0f) : hv[1];
            const float r2 = isMu ? fmaxf(hv[2], 0.0f) : hv[2];
            const float r3 = isMu ? fmaxf(hv[3], 0.0f) : hv[3];
            const float t0 = isMu ? (r0 - r1) : r0;
            const float t1 = isMu ? (r2 - r3) : r1;
            const float t2 = isMu ? 0.0f      : r2;
            const float ssum = t0*t0 + t1*t1 + t2*t2;
            const float r  = rsqrtf(ssum + 1e-16f);
            const float sc = isMu ? fminf(r, 1.0f) : r;
            if (g == 0) {
                pl0[pt] = r0 * sc;
                pl1[pt] = r1 * sc;
                pl2[pt] = r2 * sc;
                pl3[pt] = r3 * sc;
            } else if (g == 1) {
                pl4[pt] = r0 * sc;
                pl5[pt] = r1 * sc;
                pl6[pt] = r2 * sc;
            }
        }

        Pc0 = Pn0;
        Pc1 = Pn1;
    }
}

extern "C" void kernel_launch(void* const* d_in, const int* in_sizes, int n_in,
                              void* d_out, int out_size, void* d_ws, size_t ws_size,
                              hipStream_t stream) {
    const float* pc   = (const float*)d_in[0];
    const float* W1   = (const float*)d_in[1];
    const float* b1   = (const float*)d_in[2];
    const float* W2   = (const float*)d_in[3];
    const float* b2   = (const float*)d_in[4];
    const float* W3   = (const float*)d_in[5];
    const float* b3   = (const float*)d_in[6];
    const float* Wmu  = (const float*)d_in[7];
    const float* bmu  = (const float*)d_in[8];
    const float* Wlam = (const float*)d_in[9];
    const float* blam = (const float*)d_in[10];
    float* out = (float*)d_out;

    const int N = in_sizes[0] / 2;   // point_cloud is (N, 2)
    // 512 blocks x 4 waves = 2048 waves: one full resident pass at 2 waves/SIMD
    pihp_mfma<<<512, 256, 0, stream>>>(pc, W1, b1, W2, b2, W3, b3,
                                       Wmu, bmu, Wlam, blam, out, N);
}